// Round 8
// baseline (22.637 us; speedup 1.0000x reference)
//
#include <hip/hip_runtime.h>

// CLUB loss, algebraically collapsed to O(N*d) streaming reductions:
//   loss = -0.5/N * S_pos + 0.5/N^2 * ( dot(S_invv,S_x2) - 2*dot(S_muinvv,S_x) + N*S_c )
// Single kernel, last-block-done, fence-free (R6 structure, proven 17.6us).
// R8 delta (one variable): GRID 256 -> 512 (32-row tiles) for 2 blocks/CU
// = 2 waves/SIMD latency hiding. Everything else identical to R6.

#define NROWS 16384
#define DDIM  64
#define GRID  512           // one 32-row tile per block
#define ROWS  32
#define NCOL  258           // 4*64 vector partials + {S_c, S_pos}
#define NREP  4             // accumulator replicas (128-way contention each)

__device__ double g_acc[NREP * NCOL];   // zero at module load; self-reset each run
__device__ int    g_counter = 0;

__global__ __launch_bounds__(256) void club_fused(const float* __restrict__ x,
                                                  const float* __restrict__ mu,
                                                  const float* __restrict__ logvar,
                                                  float* __restrict__ out) {
    __shared__ float  xt[64 * 33];   // x tile [d][row], stride 33: bank=(d+j)%32, 2-way = free
    __shared__ double red[256];
    __shared__ double S[NCOL];
    __shared__ int    is_last;

    const int tid = threadIdx.x;
    const int bid = blockIdx.x;
    const int i0  = bid * ROWS;
    const int b   = i0 >> 10;        // h*w = 1024 rows per batch image
    const int hw0 = i0 & 1023;       // multiple of 32 -> 128B aligned

    // ---- phase 1a: stage x[b, :, hw0:hw0+32] into LDS (coalesced float4) ----
    const float* xb = x + (size_t)b * 65536 + hw0;
    #pragma unroll
    for (int c = 0; c < 2; ++c) {
        const int f  = tid + 256 * c;        // 512 float4s: f -> (dd, j4)
        const int dd = f >> 3, j4 = (f & 7) * 4;
        const float4 v = *(const float4*)(xb + (size_t)dd * 1024 + j4);
        float* p = &xt[dd * 33 + j4];        // scalar stores: 2-way banks = free
        p[0] = v.x; p[1] = v.y; p[2] = v.z; p[3] = v.w;
    }
    __syncthreads();

    // ---- phase 1b: per-thread partials (lane=d -> coalesced mu/logvar) ----
    const int d  = tid & 63;
    const int j0 = (tid >> 6) * 8;          // 4 waves x 8 rows
    double a_x = 0.0, a_x2 = 0.0, a_iv = 0.0, a_miv = 0.0, a_c = 0.0, a_pos = 0.0;
    const int base_idx = (i0 + j0) * DDIM + d;
    #pragma unroll
    for (int k = 0; k < 8; ++k) {
        const float xv = xt[d * 33 + j0 + k];
        const float m  = mu[base_idx + k * DDIM];
        const float lv = logvar[base_idx + k * DDIM];
        const float iv = expf(-lv);
        const float t2 = xv - m;
        a_x   += (double)xv;
        a_x2  += (double)(xv * xv);
        a_iv  += (double)iv;
        a_miv += (double)(m * iv);
        a_c   += (double)(m * m * iv);
        a_pos += (double)(t2 * t2 * iv);
    }

    // ---- block reduce (4 threads per d) + replicated atomic fan-in ----
    double* acc = g_acc + (size_t)(bid & (NREP - 1)) * NCOL;

    #define VR(val, base)                                                              \
        red[tid] = (val); __syncthreads();                                             \
        if (tid < 64) atomicAdd(&acc[(base) + tid],                                    \
            red[tid] + red[tid + 64] + red[tid + 128] + red[tid + 192]);               \
        __syncthreads();
    VR(a_x,   0)
    VR(a_x2,  64)
    VR(a_iv,  128)
    VR(a_miv, 192)
    #undef VR

    red[tid] = a_c; __syncthreads();
    if (tid < 64) {
        double s = red[tid] + red[tid + 64] + red[tid + 128] + red[tid + 192];
        #pragma unroll
        for (int off = 32; off > 0; off >>= 1) s += __shfl_down(s, off, 64);
        if (tid == 0) atomicAdd(&acc[256], s);
    }
    __syncthreads();
    red[tid] = a_pos; __syncthreads();
    if (tid < 64) {
        double s = red[tid] + red[tid + 64] + red[tid + 128] + red[tid + 192];
        #pragma unroll
        for (int off = 32; off > 0; off >>= 1) s += __shfl_down(s, off, 64);
        if (tid == 0) atomicAdd(&acc[257], s);
    }

    // ---- last-block election (fence-free release: drain own atomics) ----
    asm volatile("s_waitcnt vmcnt(0)" ::: "memory");
    __syncthreads();
    if (tid == 0) {
        is_last = (atomicAdd(&g_counter, 1) == GRID - 1);
        if (is_last) atomicExch(&g_counter, 0);   // reset for next replay
    }
    __syncthreads();
    if (!is_last) return;

    // ---- O(1) tail: 8 KB coherent gather + reset (agent-scope atomics) ----
    for (int c = tid; c < NCOL; c += 256) {
        double s = 0.0;
        #pragma unroll
        for (int r = 0; r < NREP; ++r) {
            s += __hip_atomic_load(&g_acc[r * NCOL + c],
                                   __ATOMIC_RELAXED, __HIP_MEMORY_SCOPE_AGENT);
            __hip_atomic_store(&g_acc[r * NCOL + c], 0.0,
                               __ATOMIC_RELAXED, __HIP_MEMORY_SCOPE_AGENT);
        }
        S[c] = s;
    }
    __syncthreads();

    // ---- final dot + scalar ----
    if (tid < 64) {
        double term = S[128 + tid] * S[64 + tid] - 2.0 * S[192 + tid] * S[tid];
        #pragma unroll
        for (int off = 32; off > 0; off >>= 1) term += __shfl_down(term, off, 64);
        if (tid == 0) {
            const double Nd   = (double)NROWS;
            const double sumD = term + Nd * S[256];
            out[0] = (float)(-0.5 / Nd * S[257] + 0.5 / (Nd * Nd) * sumD);
        }
    }
}

extern "C" void kernel_launch(void* const* d_in, const int* in_sizes, int n_in,
                              void* d_out, int out_size, void* d_ws, size_t ws_size,
                              hipStream_t stream) {
    const float* x      = (const float*)d_in[0];
    const float* mu     = (const float*)d_in[1];
    const float* logvar = (const float*)d_in[2];
    float* out = (float*)d_out;

    club_fused<<<GRID, 256, 0, stream>>>(x, mu, logvar, out);
}

// Round 9
// 20.580 us; speedup vs baseline: 1.0999x; 1.0999x over previous
//
#include <hip/hip_runtime.h>

// CLUB loss, algebraically collapsed to O(N*d) streaming reductions:
//   loss = -0.5/N * S_pos + 0.5/N^2 * ( dot(S_invv,S_x2) - 2*dot(S_muinvv,S_x) + N*S_c )
// Single kernel, last-block-done, fence-free (R6 structure, proven 17.6us).
// R9 delta (one variable): NREP 4 -> 16 (atomic same-address contention 64 -> 16).

#define NROWS 16384
#define DDIM  64
#define GRID  256           // one 64-row tile per block
#define NCOL  258           // 4*64 vector partials + {S_c, S_pos}
#define NREP  16            // accumulator replicas (16-way contention each)

__device__ double g_acc[NREP * NCOL];   // zero at module load; self-reset each run
__device__ int    g_counter = 0;

__global__ __launch_bounds__(256) void club_fused(const float* __restrict__ x,
                                                  const float* __restrict__ mu,
                                                  const float* __restrict__ logvar,
                                                  float* __restrict__ out) {
    __shared__ float  xt[64 * 65];   // padded x tile: 2-way bank access everywhere (free)
    __shared__ double red[256];
    __shared__ double S[NCOL];
    __shared__ int    is_last;

    const int tid = threadIdx.x;
    const int bid = blockIdx.x;
    const int i0  = bid * 64;
    const int b   = i0 >> 10;        // h*w = 1024 rows per batch image
    const int hw0 = i0 & 1023;       // multiple of 64

    // ---- phase 1a: stage x[b, :, hw0:hw0+64] into LDS (coalesced float4) ----
    const float* xb = x + (size_t)b * 65536 + hw0;
    #pragma unroll
    for (int t = tid; t < 1024; t += 256) {
        const int dd = t >> 4, j4 = (t & 15) * 4;
        const float4 v = *(const float4*)(xb + (size_t)dd * 1024 + j4);
        float* p = &xt[dd * 65 + j4];
        p[0] = v.x; p[1] = v.y; p[2] = v.z; p[3] = v.w;
    }
    __syncthreads();

    // ---- phase 1b: per-thread partials (lane=d -> coalesced mu/logvar) ----
    const int d  = tid & 63;
    const int j0 = (tid >> 6) * 16;
    double a_x = 0.0, a_x2 = 0.0, a_iv = 0.0, a_miv = 0.0, a_c = 0.0, a_pos = 0.0;
    const int base_idx = (i0 + j0) * DDIM + d;
    #pragma unroll
    for (int k = 0; k < 16; ++k) {
        const float xv = xt[d * 65 + j0 + k];
        const float m  = mu[base_idx + k * DDIM];
        const float lv = logvar[base_idx + k * DDIM];
        const float iv = expf(-lv);
        const float t2 = xv - m;
        a_x   += (double)xv;
        a_x2  += (double)(xv * xv);
        a_iv  += (double)iv;
        a_miv += (double)(m * iv);
        a_c   += (double)(m * m * iv);
        a_pos += (double)(t2 * t2 * iv);
    }

    // ---- block reduce (4 threads per d) + replicated atomic fan-in ----
    double* acc = g_acc + (size_t)(bid & (NREP - 1)) * NCOL;

    #define VR(val, base)                                                              \
        red[tid] = (val); __syncthreads();                                             \
        if (tid < 64) atomicAdd(&acc[(base) + tid],                                    \
            red[tid] + red[tid + 64] + red[tid + 128] + red[tid + 192]);               \
        __syncthreads();
    VR(a_x,   0)
    VR(a_x2,  64)
    VR(a_iv,  128)
    VR(a_miv, 192)
    #undef VR

    red[tid] = a_c; __syncthreads();
    if (tid < 64) {
        double s = red[tid] + red[tid + 64] + red[tid + 128] + red[tid + 192];
        #pragma unroll
        for (int off = 32; off > 0; off >>= 1) s += __shfl_down(s, off, 64);
        if (tid == 0) atomicAdd(&acc[256], s);
    }
    __syncthreads();
    red[tid] = a_pos; __syncthreads();
    if (tid < 64) {
        double s = red[tid] + red[tid + 64] + red[tid + 128] + red[tid + 192];
        #pragma unroll
        for (int off = 32; off > 0; off >>= 1) s += __shfl_down(s, off, 64);
        if (tid == 0) atomicAdd(&acc[257], s);
    }

    // ---- last-block election (fence-free release: drain own atomics) ----
    asm volatile("s_waitcnt vmcnt(0)" ::: "memory");
    __syncthreads();
    if (tid == 0) {
        is_last = (atomicAdd(&g_counter, 1) == GRID - 1);
        if (is_last) atomicExch(&g_counter, 0);   // reset for next replay
    }
    __syncthreads();
    if (!is_last) return;

    // ---- O(1) tail: 32 KB coherent gather + reset (agent-scope atomics) ----
    for (int c = tid; c < NCOL; c += 256) {
        double s = 0.0;
        #pragma unroll
        for (int r = 0; r < NREP; ++r) {
            s += __hip_atomic_load(&g_acc[r * NCOL + c],
                                   __ATOMIC_RELAXED, __HIP_MEMORY_SCOPE_AGENT);
            __hip_atomic_store(&g_acc[r * NCOL + c], 0.0,
                               __ATOMIC_RELAXED, __HIP_MEMORY_SCOPE_AGENT);
        }
        S[c] = s;
    }
    __syncthreads();

    // ---- final dot + scalar ----
    if (tid < 64) {
        double term = S[128 + tid] * S[64 + tid] - 2.0 * S[192 + tid] * S[tid];
        #pragma unroll
        for (int off = 32; off > 0; off >>= 1) term += __shfl_down(term, off, 64);
        if (tid == 0) {
            const double Nd   = (double)NROWS;
            const double sumD = term + Nd * S[256];
            out[0] = (float)(-0.5 / Nd * S[257] + 0.5 / (Nd * Nd) * sumD);
        }
    }
}

extern "C" void kernel_launch(void* const* d_in, const int* in_sizes, int n_in,
                              void* d_out, int out_size, void* d_ws, size_t ws_size,
                              hipStream_t stream) {
    const float* x      = (const float*)d_in[0];
    const float* mu     = (const float*)d_in[1];
    const float* logvar = (const float*)d_in[2];
    float* out = (float*)d_out;

    club_fused<<<GRID, 256, 0, stream>>>(x, mu, logvar, out);
}

// Round 10
// 17.551 us; speedup vs baseline: 1.2897x; 1.1725x over previous
//
#include <hip/hip_runtime.h>

// CLUB loss, algebraically collapsed to O(N*d) streaming reductions:
//   loss = -0.5/N * S_pos + 0.5/N^2 * ( dot(S_invv,S_x2) - 2*dot(S_muinvv,S_x) + N*S_c )
// Single kernel, last-block-done, fence-free. This is the R6 configuration
// (proven best: 17.6us) reverted verbatim after R7/R8/R9 single-variable
// probes (grid x2: +5us, NREP 16: +3us) all regressed.

#define NROWS 16384
#define DDIM  64
#define GRID  256           // one 64-row tile per block
#define NCOL  258           // 4*64 vector partials + {S_c, S_pos}
#define NREP  4             // accumulator replicas (64-way contention each)

__device__ double g_acc[NREP * NCOL];   // zero at module load; self-reset each run
__device__ int    g_counter = 0;

__global__ __launch_bounds__(256) void club_fused(const float* __restrict__ x,
                                                  const float* __restrict__ mu,
                                                  const float* __restrict__ logvar,
                                                  float* __restrict__ out) {
    __shared__ float  xt[64 * 65];   // padded x tile: 2-way bank access everywhere (free)
    __shared__ double red[256];
    __shared__ double S[NCOL];
    __shared__ int    is_last;

    const int tid = threadIdx.x;
    const int bid = blockIdx.x;
    const int i0  = bid * 64;
    const int b   = i0 >> 10;        // h*w = 1024 rows per batch image
    const int hw0 = i0 & 1023;       // multiple of 64

    // ---- phase 1a: stage x[b, :, hw0:hw0+64] into LDS (coalesced float4) ----
    const float* xb = x + (size_t)b * 65536 + hw0;
    #pragma unroll
    for (int t = tid; t < 1024; t += 256) {
        const int dd = t >> 4, j4 = (t & 15) * 4;
        const float4 v = *(const float4*)(xb + (size_t)dd * 1024 + j4);
        float* p = &xt[dd * 65 + j4];
        p[0] = v.x; p[1] = v.y; p[2] = v.z; p[3] = v.w;
    }
    __syncthreads();

    // ---- phase 1b: per-thread partials (lane=d -> coalesced mu/logvar) ----
    const int d  = tid & 63;
    const int j0 = (tid >> 6) * 16;
    double a_x = 0.0, a_x2 = 0.0, a_iv = 0.0, a_miv = 0.0, a_c = 0.0, a_pos = 0.0;
    const int base_idx = (i0 + j0) * DDIM + d;
    #pragma unroll
    for (int k = 0; k < 16; ++k) {
        const float xv = xt[d * 65 + j0 + k];
        const float m  = mu[base_idx + k * DDIM];
        const float lv = logvar[base_idx + k * DDIM];
        const float iv = expf(-lv);
        const float t2 = xv - m;
        a_x   += (double)xv;
        a_x2  += (double)(xv * xv);
        a_iv  += (double)iv;
        a_miv += (double)(m * iv);
        a_c   += (double)(m * m * iv);
        a_pos += (double)(t2 * t2 * iv);
    }

    // ---- block reduce (4 threads per d) + replicated atomic fan-in ----
    double* acc = g_acc + (size_t)(bid & (NREP - 1)) * NCOL;

    #define VR(val, base)                                                              \
        red[tid] = (val); __syncthreads();                                             \
        if (tid < 64) atomicAdd(&acc[(base) + tid],                                    \
            red[tid] + red[tid + 64] + red[tid + 128] + red[tid + 192]);               \
        __syncthreads();
    VR(a_x,   0)
    VR(a_x2,  64)
    VR(a_iv,  128)
    VR(a_miv, 192)
    #undef VR

    red[tid] = a_c; __syncthreads();
    if (tid < 64) {
        double s = red[tid] + red[tid + 64] + red[tid + 128] + red[tid + 192];
        #pragma unroll
        for (int off = 32; off > 0; off >>= 1) s += __shfl_down(s, off, 64);
        if (tid == 0) atomicAdd(&acc[256], s);
    }
    __syncthreads();
    red[tid] = a_pos; __syncthreads();
    if (tid < 64) {
        double s = red[tid] + red[tid + 64] + red[tid + 128] + red[tid + 192];
        #pragma unroll
        for (int off = 32; off > 0; off >>= 1) s += __shfl_down(s, off, 64);
        if (tid == 0) atomicAdd(&acc[257], s);
    }

    // ---- last-block election (fence-free release: drain own atomics) ----
    asm volatile("s_waitcnt vmcnt(0)" ::: "memory");
    __syncthreads();
    if (tid == 0) {
        is_last = (atomicAdd(&g_counter, 1) == GRID - 1);
        if (is_last) atomicExch(&g_counter, 0);   // reset for next replay
    }
    __syncthreads();
    if (!is_last) return;

    // ---- O(1) tail: 8 KB coherent gather + reset (agent-scope atomics) ----
    for (int c = tid; c < NCOL; c += 256) {
        double s = 0.0;
        #pragma unroll
        for (int r = 0; r < NREP; ++r) {
            s += __hip_atomic_load(&g_acc[r * NCOL + c],
                                   __ATOMIC_RELAXED, __HIP_MEMORY_SCOPE_AGENT);
            __hip_atomic_store(&g_acc[r * NCOL + c], 0.0,
                               __ATOMIC_RELAXED, __HIP_MEMORY_SCOPE_AGENT);
        }
        S[c] = s;
    }
    __syncthreads();

    // ---- final dot + scalar ----
    if (tid < 64) {
        double term = S[128 + tid] * S[64 + tid] - 2.0 * S[192 + tid] * S[tid];
        #pragma unroll
        for (int off = 32; off > 0; off >>= 1) term += __shfl_down(term, off, 64);
        if (tid == 0) {
            const double Nd   = (double)NROWS;
            const double sumD = term + Nd * S[256];
            out[0] = (float)(-0.5 / Nd * S[257] + 0.5 / (Nd * Nd) * sumD);
        }
    }
}

extern "C" void kernel_launch(void* const* d_in, const int* in_sizes, int n_in,
                              void* d_out, int out_size, void* d_ws, size_t ws_size,
                              hipStream_t stream) {
    const float* x      = (const float*)d_in[0];
    const float* mu     = (const float*)d_in[1];
    const float* logvar = (const float*)d_in[2];
    float* out = (float*)d_out;

    club_fused<<<GRID, 256, 0, stream>>>(x, mu, logvar, out);
}